// Round 1
// baseline (66558.868 us; speedup 1.0000x reference)
//
#include <hip/hip_runtime.h>
#include <hip/hip_bf16.h>

typedef __attribute__((ext_vector_type(8))) short bf16x8;
typedef __attribute__((ext_vector_type(4))) float f32x4;

#define Tn 1024
#define Bn 64
#define Hn 2048
#define NBLK 256

__device__ __forceinline__ unsigned short f2b(float x) {
    // fp32 -> bf16 round-to-nearest-even
    unsigned u = __float_as_uint(x);
    unsigned r = (u + 0x7fffu + ((u >> 16) & 1u)) >> 16;
    return (unsigned short)r;
}

__device__ __forceinline__ float sigm(float x) {
    return __builtin_amdgcn_rcpf(1.0f + __expf(-x));
}
__device__ __forceinline__ float tanh_f(float x) {
    // 1 - 2/(e^{2x}+1): stable at +/-inf
    float e = __expf(2.0f * x);
    return 1.0f - 2.0f * __builtin_amdgcn_rcpf(1.0f + e);
}

// Prep: W_hh fp32 -> bf16 copy in ws; init_hidden -> bf16 h0; zero barrier.
__global__ void prep_kernel(const float* __restrict__ w_hh,
                            const float* __restrict__ init_h,
                            unsigned short* __restrict__ w_bf,
                            unsigned short* __restrict__ h0,
                            unsigned* __restrict__ bar) {
    const long i = (long)blockIdx.x * blockDim.x + threadIdx.x;
    const long i4 = i * 4;
    if (i4 < 12582912L) {  // 3H*H
        float4 v = *reinterpret_cast<const float4*>(w_hh + i4);
        ushort4 o;
        o.x = f2b(v.x); o.y = f2b(v.y); o.z = f2b(v.z); o.w = f2b(v.w);
        *reinterpret_cast<ushort4*>(w_bf + i4) = o;
    }
    if (i4 < 131072L) {    // B*H
        float4 v = *reinterpret_cast<const float4*>(init_h + i4);
        ushort4 o;
        o.x = f2b(v.x); o.y = f2b(v.y); o.z = f2b(v.z); o.w = f2b(v.w);
        *reinterpret_cast<ushort4*>(h0 + i4) = o;
    }
    if (i == 0) *bar = 0u;
}

// Persistent GRU kernel. 256 blocks x 256 threads (4 waves).
// Block bk owns hidden units j in [8*bk, 8*bk+8).
// Wave w: kh = w>>1 (K-half), g = w&1 (batch half: M-tiles {2g,2g+1}).
// Per wave: C[32 x 32pad] partial over its K-half via mfma_f32_16x16x32_bf16.
//   N-tile0 cols: 0-7 = r-gate rows (j0+n), 8-15 = z-gate rows (H+j0+n-8)
//   N-tile1 cols: 0-7 = n-gate rows (2H+j0+n), 8-15 = pad (dup, ignored)
// fp32 hidden state lives in registers of kh==0 waves, lanes (lane&15)<8,
// exactly at the MFMA C-layout position (b = 32g+16mt+quad*4+r, j = j0+(lane&7)).
__global__ void __launch_bounds__(256) gru_kernel(
    const float* __restrict__ inp,     // [T][B][3]
    const float* __restrict__ init_h,  // [B][H]
    const float* __restrict__ w_ih,    // [3H][3]
    const float* __restrict__ bias,    // [3H]
    const float* __restrict__ bias_n,  // [H]
    const unsigned short* __restrict__ w_bf,  // [3H][H] bf16
    unsigned short* __restrict__ h0,   // [B][H] bf16 double buffer
    unsigned short* __restrict__ h1,
    unsigned* __restrict__ bar,
    float* __restrict__ out)           // [T][B]
{
    __shared__ float redbuf[2][16][64];  // cross-K-half partial exchange

    const int tid  = threadIdx.x;
    const int lane = tid & 63;
    const int wave = tid >> 6;
    const int quad = lane >> 4;
    const int n16  = lane & 15;
    const int kh   = wave >> 1;
    const int g    = wave & 1;
    const int j0   = blockIdx.x * 8;
    const int jj   = n16 & 7;

    // B-frag source rows in W (bf16, row-major [3H][H])
    const int rowN0 = (n16 < 8) ? (j0 + n16) : (Hn + j0 + n16 - 8);
    const int rowN1 = 2 * Hn + j0 + jj;   // dup for n16>=8 (ignored)

    const int kbase = kh * 1024 + quad * 8;
    const int bA0 = 32 * g + n16;       // A-frag row, M-tile 0
    const int bA1 = bA0 + 16;           // M-tile 1

    // Epilogue constants (valid where used: kh==0, n16<8)
    const int jg = j0 + jj;
    float wr0 = w_ih[jg*3+0], wr1 = w_ih[jg*3+1], wr2 = w_ih[jg*3+2];
    float wz0 = w_ih[(Hn+jg)*3+0], wz1 = w_ih[(Hn+jg)*3+1], wz2 = w_ih[(Hn+jg)*3+2];
    float wn0 = w_ih[(2*Hn+jg)*3+0], wn1 = w_ih[(2*Hn+jg)*3+1], wn2 = w_ih[(2*Hn+jg)*3+2];
    float br_ = bias[jg], bz_ = bias[Hn+jg], bn2_ = bias[2*Hn+jg];
    float bnn_ = bias_n[jg];

    // fp32 hidden state registers
    float hst[2][4];
    #pragma unroll
    for (int mt = 0; mt < 2; ++mt)
        #pragma unroll
        for (int r = 0; r < 4; ++r)
            hst[mt][r] = init_h[(32*g + 16*mt + quad*4 + r) * Hn + jg];

    unsigned target = NBLK;
    for (int t = 0; t < Tn; ++t) {
        const unsigned short* hcur = (t & 1) ? h1 : h0;
        unsigned short* hnext      = (t & 1) ? h0 : h1;

        f32x4 acc00 = {0.f,0.f,0.f,0.f}, acc01 = {0.f,0.f,0.f,0.f};
        f32x4 acc10 = {0.f,0.f,0.f,0.f}, acc11 = {0.f,0.f,0.f,0.f};

        const unsigned short* pa0 = hcur + bA0 * Hn + kbase;
        const unsigned short* pa1 = hcur + bA1 * Hn + kbase;
        const unsigned short* pb0 = w_bf + (long)rowN0 * Hn + kbase;
        const unsigned short* pb1 = w_bf + (long)rowN1 * Hn + kbase;

        #pragma unroll 4
        for (int k = 0; k < 1024; k += 32) {
            bf16x8 a0 = *(const bf16x8*)(pa0 + k);
            bf16x8 a1 = *(const bf16x8*)(pa1 + k);
            bf16x8 b0 = *(const bf16x8*)(pb0 + k);
            bf16x8 b1 = *(const bf16x8*)(pb1 + k);
            acc00 = __builtin_amdgcn_mfma_f32_16x16x32_bf16(a0, b0, acc00, 0, 0, 0);
            acc01 = __builtin_amdgcn_mfma_f32_16x16x32_bf16(a0, b1, acc01, 0, 0, 0);
            acc10 = __builtin_amdgcn_mfma_f32_16x16x32_bf16(a1, b0, acc10, 0, 0, 0);
            acc11 = __builtin_amdgcn_mfma_f32_16x16x32_bf16(a1, b1, acc11, 0, 0, 0);
        }

        // cross-K-half reduction: kh==1 waves dump partials, kh==0 waves add
        if (kh == 1) {
            #pragma unroll
            for (int r = 0; r < 4; ++r) {
                redbuf[g][0 + r][lane]  = acc00[r];
                redbuf[g][4 + r][lane]  = acc01[r];
                redbuf[g][8 + r][lane]  = acc10[r];
                redbuf[g][12 + r][lane] = acc11[r];
            }
        }
        __syncthreads();
        if (kh == 0) {
            #pragma unroll
            for (int r = 0; r < 4; ++r) {
                acc00[r] += redbuf[g][0 + r][lane];
                acc01[r] += redbuf[g][4 + r][lane];
                acc10[r] += redbuf[g][8 + r][lane];
                acc11[r] += redbuf[g][12 + r][lane];
            }
            #pragma unroll
            for (int mt = 0; mt < 2; ++mt) {
                #pragma unroll
                for (int r = 0; r < 4; ++r) {
                    float rdot = mt ? acc10[r] : acc00[r];
                    float ndot = mt ? acc11[r] : acc01[r];
                    float zdot = __shfl_xor(rdot, 8, 64);  // all lanes execute
                    if (n16 < 8) {
                        int b = 32*g + 16*mt + quad*4 + r;
                        const float* xp = inp + ((long)t * Bn + b) * 3;
                        float x0 = xp[0], x1 = xp[1], x2 = xp[2];
                        float pr = br_ + wr0*x0 + wr1*x1 + wr2*x2 + rdot;
                        float pz = bz_ + wz0*x0 + wz1*x1 + wz2*x2 + zdot;
                        float rr = sigm(pr);
                        float zz = sigm(pz);
                        float pn = bn2_ + wn0*x0 + wn1*x1 + wn2*x2 + rr*(ndot + bnn_);
                        float nn = tanh_f(pn);
                        float hv = nn + zz * (hst[mt][r] - nn);
                        hst[mt][r] = hv;
                        hnext[b * Hn + jg] = f2b(hv);
                        if (jg == 0) out[t * Bn + b] = hv;
                    }
                }
            }
        }

        // ---- grid barrier (monotonic counter, no reset) ----
        __syncthreads();     // also orders redbuf reads vs next-step writes
        __threadfence();     // release h writes (L2-visible, device scope)
        if (tid == 0) {
            __hip_atomic_fetch_add(bar, 1u, __ATOMIC_RELEASE, __HIP_MEMORY_SCOPE_AGENT);
            while (__hip_atomic_load(bar, __ATOMIC_ACQUIRE, __HIP_MEMORY_SCOPE_AGENT) < target) {
                __builtin_amdgcn_s_sleep(1);
            }
        }
        __syncthreads();
        __threadfence();     // acquire: invalidate L1 so fresh h is visible
        target += NBLK;
    }
}

extern "C" void kernel_launch(void* const* d_in, const int* in_sizes, int n_in,
                              void* d_out, int out_size, void* d_ws, size_t ws_size,
                              hipStream_t stream) {
    const float* inp    = (const float*)d_in[0];  // [1024][64][3]
    const float* init_h = (const float*)d_in[1];  // [64][2048]
    const float* w_ih   = (const float*)d_in[2];  // [6144][3]
    const float* w_hh   = (const float*)d_in[3];  // [6144][2048]
    const float* bias   = (const float*)d_in[4];  // [6144]
    const float* bias_n = (const float*)d_in[5];  // [2048]
    float* out = (float*)d_out;                   // [1024][64]

    unsigned short* w_bf = (unsigned short*)d_ws;          // 25165824 B
    unsigned short* h0   = w_bf + 12582912L;               // 262144 B
    unsigned short* h1   = h0 + 131072L;                   // 262144 B
    unsigned* bar        = (unsigned*)(h1 + 131072L);      // 4 B

    prep_kernel<<<12288, 256, 0, stream>>>(w_hh, init_h, w_bf, h0, bar);
    gru_kernel<<<NBLK, 256, 0, stream>>>(inp, init_h, w_ih, bias, bias_n,
                                         w_bf, h0, h1, bar, out);
}